// Round 11
// baseline (100.033 us; speedup 1.0000x reference)
//
#include <hip/hip_runtime.h>
#include <math.h>

// Problem constants (match reference)
constexpr int B = 8, S = 128, T = 4096;
constexpr int NPIX = 256 * 256;          // NX*NY

// Kernel 0: time-of-flight index table — hypothesis: XLA CPU f32 chain with
// the algebraic-simplifier rewrite  x / const  ->  x * fl32(1/const):
//   ax = fl32(|dx| * fl32(1e-3))         (sub exact, mul correctly rounded)
//   d2 = fl32(fl32(ax^2) + fl32(ay^2))   (eager per-op: NO FMA -> barriered)
//   dis = fl32(sqrt(d2))                 (correctly rounded)
//   q1 = fl32(dis * fl32(1/1550))        (NOT a division!)
//   tf = fl32(q1 * 1e7f)                 (fl32(1/fl32(1e-7)) == 1e7 exactly)
//   t  = trunc(tf)
// t depends only on (|dx|,|dy|): fl(-a*c) = -fl(a*c), squaring kills sign,
// so a 256x256 table covers all (sensor,pixel) pairs.
__global__ __launch_bounds__(256) void build_tab(unsigned short* __restrict__ tab) {
    constexpr float RVS = 1.0f / 1550.0f;    // compile-time correctly-rounded f32
    constexpr float RDT = 1.0e7f;            // fl32(1/fl32(1e-7)) == 1e7 (exact)
    int i = blockIdx.x * 256 + threadIdx.x;
    float ax = (float)(i >> 8) * 1e-3f;      // fl32(dx * fl32(1e-3))
    float ay = (float)(i & 255) * 1e-3f;
    float px = ax * ax;
    float py = ay * ay;
    asm volatile("" : "+v"(px));             // pin rounded squares: forbid FMA
    asm volatile("" : "+v"(py));
    float d2  = px + py;                     // plain v_add_f32
    float dis = __fsqrt_rn(d2);              // correctly-rounded f32 sqrt
    float q1  = __fmul_rn(dis, RVS);         // dis * (1/1550)
    asm volatile("" : "+v"(q1));             // forbid re-association of the muls
    float tf  = __fmul_rn(q1, RDT);          // * 1e7
    tab[i] = (unsigned short)(int)tf;        // t_max ~ 2326 < 4096
}

// Kernel A: delay-and-sum accumulation. 1 thread/pixel, pure-integer index
// math via the table, 8 batch accumulators in FP64 (order-insensitive to
// well below the comparison threshold).
__global__ __launch_bounds__(256) void das_accum(const float* __restrict__ data,
                                                 const int* __restrict__ sxy,
                                                 const unsigned short* __restrict__ tab,
                                                 float* __restrict__ out) {
    __shared__ int sx[S], sy[S];
    int tid = threadIdx.x;
    if (tid < S) {
        sx[tid] = sxy[2 * tid];
        sy[tid] = sxy[2 * tid + 1];
    }
    __syncthreads();

    int ix = blockIdx.x;                  // pixel row
    int iy = tid;                         // pixel col
    int p  = (ix << 8) + iy;

    double acc[B];
#pragma unroll
    for (int b = 0; b < B; ++b) acc[b] = 0.0;

    for (int s = 0; s < S; ++s) {
        int dxi = abs(sx[s] - ix);
        int dyi = abs(sy[s] - iy);
        int t = (int)tab[(dxi << 8) + dyi];
        const float* row = data + s * T + t;
#pragma unroll
        for (int b = 0; b < B; ++b) acc[b] += (double)row[b * (S * T)];
    }

#pragma unroll
    for (int b = 0; b < B; ++b) out[b * NPIX + p] = (float)acc[b];
}

// Kernel B: per-batch min/max reduction -> mm[2*b], mm[2*b+1]
__global__ __launch_bounds__(1024) void das_minmax(const float* __restrict__ img,
                                                   float* __restrict__ mm) {
    int b = blockIdx.x;
    const float* p = img + b * NPIX;
    float mn = 3.0e38f, mx = -3.0e38f;
    for (int i = threadIdx.x; i < NPIX; i += 1024) {
        float v = p[i];
        mn = fminf(mn, v);
        mx = fmaxf(mx, v);
    }
    for (int off = 32; off; off >>= 1) {
        mn = fminf(mn, __shfl_down(mn, off));
        mx = fmaxf(mx, __shfl_down(mx, off));
    }
    __shared__ float smn[16], smx[16];
    int w = threadIdx.x >> 6;
    if ((threadIdx.x & 63) == 0) { smn[w] = mn; smx[w] = mx; }
    __syncthreads();
    if (threadIdx.x < 16) {
        mn = smn[threadIdx.x];
        mx = smx[threadIdx.x];
        for (int off = 8; off; off >>= 1) {
            mn = fminf(mn, __shfl_down(mn, off));
            mx = fmaxf(mx, __shfl_down(mx, off));
        }
        if (threadIdx.x == 0) { mm[2 * b] = mn; mm[2 * b + 1] = mx; }
    }
}

// Kernel C: in-place per-batch min-max normalization
__global__ __launch_bounds__(256) void das_norm(float* __restrict__ out,
                                                const float* __restrict__ mm) {
    int i = blockIdx.x * 256 + threadIdx.x;
    int b = i >> 16;                      // / NPIX
    float mn = mm[2 * b];
    float mx = mm[2 * b + 1];
    out[i] = __fdiv_rn(__fsub_rn(out[i], mn), __fsub_rn(mx, mn));
}

extern "C" void kernel_launch(void* const* d_in, const int* in_sizes, int n_in,
                              void* d_out, int out_size, void* d_ws, size_t ws_size,
                              hipStream_t stream) {
    const float* data = (const float*)d_in[0];   // (B, S, T) fp32
    const int*   sxy  = (const int*)d_in[1];     // (S, 2) int32
    float* out = (float*)d_out;                  // (B, 256, 256) fp32

    // ws layout: [0, 128KB) u16 t-table; [128KB, +64B) min/max scratch
    unsigned short* tab = (unsigned short*)d_ws;
    float* mm = (float*)((char*)d_ws + NPIX * sizeof(unsigned short));

    build_tab<<<NPIX / 256, 256, 0, stream>>>(tab);
    das_accum<<<256, 256, 0, stream>>>(data, sxy, tab, out);
    das_minmax<<<B, 1024, 0, stream>>>(out, mm);
    das_norm<<<(B * NPIX) / 256, 256, 0, stream>>>(out, mm);
}

// Round 12
// 81.778 us; speedup vs baseline: 1.2232x; 1.2232x over previous
//
#include <hip/hip_runtime.h>
#include <math.h>

// Problem constants (match reference)
constexpr int B = 8, S = 128, T = 4096;
constexpr int NPIX = 256 * 256;          // NX*NY

// Kernel 0: time-of-flight index table — XLA CPU f32 chain with the
// algebraic-simplifier rewrite  x / const -> x * fl32(1/const)  (verified
// round 11: absmax 0.0039 vs ref=np).
__global__ __launch_bounds__(256) void build_tab(unsigned short* __restrict__ tab) {
    constexpr float RVS = 1.0f / 1550.0f;    // compile-time correctly-rounded f32
    constexpr float RDT = 1.0e7f;            // fl32(1/fl32(1e-7)) == 1e7 (exact)
    int i = blockIdx.x * 256 + threadIdx.x;
    float ax = (float)(i >> 8) * 1e-3f;      // fl32(dx * fl32(1e-3))
    float ay = (float)(i & 255) * 1e-3f;
    float px = ax * ax;
    float py = ay * ay;
    asm volatile("" : "+v"(px));             // pin rounded squares: forbid FMA
    asm volatile("" : "+v"(py));
    float d2  = px + py;                     // plain v_add_f32
    float dis = __fsqrt_rn(d2);              // correctly-rounded f32 sqrt
    float q1  = __fmul_rn(dis, RVS);         // dis * (1/1550)
    asm volatile("" : "+v"(q1));             // forbid re-association of the muls
    float tf  = __fmul_rn(q1, RDT);          // * 1e7
    tab[i] = (unsigned short)(int)tf;        // t_max ~ 2326 < 4096
}

// Kernel A: delay-and-sum accumulation, one thread per (batch, pixel).
// grid = B*256 blocks of 256 threads -> 8 blocks/CU -> up to 32 waves/CU
// (vs 1 block/CU in the 8-batch/thread version that measured 10.7% occupancy).
// Same s-ascending fp64 accumulation order per output => bit-identical image.
__global__ __launch_bounds__(256) void das_accum(const float* __restrict__ data,
                                                 const int* __restrict__ sxy,
                                                 const unsigned short* __restrict__ tab,
                                                 float* __restrict__ out) {
    __shared__ int sx[S], sy[S];
    int tid = threadIdx.x;
    if (tid < S) {
        sx[tid] = sxy[2 * tid];
        sy[tid] = sxy[2 * tid + 1];
    }
    __syncthreads();

    int b  = blockIdx.x >> 8;             // batch
    int ix = blockIdx.x & 255;            // pixel row
    int iy = tid;                         // pixel col
    int p  = (ix << 8) + iy;

    const float* dbase = data + b * (S * T);

    double acc = 0.0;
#pragma unroll 8
    for (int s = 0; s < S; ++s) {
        int dxi = abs(sx[s] - ix);
        int dyi = abs(sy[s] - iy);
        int t = (int)tab[(dxi << 8) + dyi];
        acc += (double)dbase[s * T + t];
    }

    out[b * NPIX + p] = (float)acc;
}

// Kernel B: per-batch min/max reduction -> mm[2*b], mm[2*b+1]
__global__ __launch_bounds__(1024) void das_minmax(const float* __restrict__ img,
                                                   float* __restrict__ mm) {
    int b = blockIdx.x;
    const float* p = img + b * NPIX;
    float mn = 3.0e38f, mx = -3.0e38f;
    for (int i = threadIdx.x; i < NPIX; i += 1024) {
        float v = p[i];
        mn = fminf(mn, v);
        mx = fmaxf(mx, v);
    }
    for (int off = 32; off; off >>= 1) {
        mn = fminf(mn, __shfl_down(mn, off));
        mx = fmaxf(mx, __shfl_down(mx, off));
    }
    __shared__ float smn[16], smx[16];
    int w = threadIdx.x >> 6;
    if ((threadIdx.x & 63) == 0) { smn[w] = mn; smx[w] = mx; }
    __syncthreads();
    if (threadIdx.x < 16) {
        mn = smn[threadIdx.x];
        mx = smx[threadIdx.x];
        for (int off = 8; off; off >>= 1) {
            mn = fminf(mn, __shfl_down(mn, off));
            mx = fmaxf(mx, __shfl_down(mx, off));
        }
        if (threadIdx.x == 0) { mm[2 * b] = mn; mm[2 * b + 1] = mx; }
    }
}

// Kernel C: in-place per-batch min-max normalization
__global__ __launch_bounds__(256) void das_norm(float* __restrict__ out,
                                                const float* __restrict__ mm) {
    int i = blockIdx.x * 256 + threadIdx.x;
    int b = i >> 16;                      // / NPIX
    float mn = mm[2 * b];
    float mx = mm[2 * b + 1];
    out[i] = __fdiv_rn(__fsub_rn(out[i], mn), __fsub_rn(mx, mn));
}

extern "C" void kernel_launch(void* const* d_in, const int* in_sizes, int n_in,
                              void* d_out, int out_size, void* d_ws, size_t ws_size,
                              hipStream_t stream) {
    const float* data = (const float*)d_in[0];   // (B, S, T) fp32
    const int*   sxy  = (const int*)d_in[1];     // (S, 2) int32
    float* out = (float*)d_out;                  // (B, 256, 256) fp32

    // ws layout: [0, 128KB) u16 t-table; [128KB, +64B) min/max scratch
    unsigned short* tab = (unsigned short*)d_ws;
    float* mm = (float*)((char*)d_ws + NPIX * sizeof(unsigned short));

    build_tab<<<NPIX / 256, 256, 0, stream>>>(tab);
    das_accum<<<B * 256, 256, 0, stream>>>(data, sxy, tab, out);
    das_minmax<<<B, 1024, 0, stream>>>(out, mm);
    das_norm<<<(B * NPIX) / 256, 256, 0, stream>>>(out, mm);
}

// Round 13
// 72.028 us; speedup vs baseline: 1.3888x; 1.1354x over previous
//
#include <hip/hip_runtime.h>
#include <math.h>

// Problem constants (match reference)
constexpr int B = 8, S = 128, T = 4096;
constexpr int NPIX = 256 * 256;          // NX*NY
constexpr float RVS = 1.0f / 1550.0f;    // compile-time correctly-rounded f32
constexpr float RDT = 1.0e7f;            // fl32(1/fl32(1e-7)) == 1e7 (exact)
constexpr int NCHUNK = 4;                // sensor chunks (32 sensors each)
constexpr size_t DT_BYTES   = (size_t)S * T * B * sizeof(float);   // 16 MB
constexpr size_t PART_BYTES = (size_t)NPIX * B * sizeof(float);    // 2 MB
constexpr size_t WS_NEED    = DT_BYTES + 3 * PART_BYTES + 64;      // ~22 MB

// Verified t-chain (round 11, absmax 0.0039): XLA f32 with x/const -> x*(1/const).
__device__ __forceinline__ int tof_index(int dxi, int dyi) {
    float ax = (float)dxi * 1e-3f;
    float ay = (float)dyi * 1e-3f;
    float px = ax * ax;
    float py = ay * ay;
    asm volatile("" : "+v"(px));         // pin rounded squares: forbid FMA
    asm volatile("" : "+v"(py));
    float d2  = px + py;
    float dis = __fsqrt_rn(d2);
    float q1  = __fmul_rn(dis, RVS);
    asm volatile("" : "+v"(q1));
    float tf  = __fmul_rn(q1, RDT);
    return (int)tf;                      // t_max ~ 2326 < 4096
}

// ---------- fast path (needs 22MB ws) ----------

// Transpose (B,S,T) -> (S,T,B): all 8 batch samples of (s,t) contiguous (32B).
__global__ __launch_bounds__(256) void das_transpose(const float* __restrict__ data,
                                                     float* __restrict__ dt) {
    int idx = blockIdx.x * 256 + threadIdx.x;     // s*T + t
    float v[B];
#pragma unroll
    for (int b = 0; b < B; ++b) v[b] = data[b * (S * T) + idx];
    float4* o = (float4*)(dt + (size_t)idx * B);
    o[0] = make_float4(v[0], v[1], v[2], v[3]);
    o[1] = make_float4(v[4], v[5], v[6], v[7]);
}

// One thread per pixel, 8 fp32 accumulators, 32 sensors per chunk.
// grid = NCHUNK*256 blocks -> 4 blocks/CU -> 16 waves/CU.
__global__ __launch_bounds__(256) void das_accum8(const float* __restrict__ dt,
                                                  const int* __restrict__ sxy,
                                                  float* __restrict__ out,
                                                  float* __restrict__ part) {
    __shared__ int sx[S], sy[S];
    int tid = threadIdx.x;
    if (tid < S) {
        sx[tid] = sxy[2 * tid];
        sy[tid] = sxy[2 * tid + 1];
    }
    __syncthreads();

    int chunk = blockIdx.x >> 8;          // 0..3
    int ix    = blockIdx.x & 255;         // pixel row
    int iy    = tid;                      // pixel col
    int p     = (ix << 8) + iy;

    float acc[B];
#pragma unroll
    for (int b = 0; b < B; ++b) acc[b] = 0.0f;

    int s0 = chunk * (S / NCHUNK);
#pragma unroll 4
    for (int s = s0; s < s0 + S / NCHUNK; ++s) {
        int t = tof_index(abs(sx[s] - ix), abs(sy[s] - iy));
        const float4* row = (const float4*)(dt + ((size_t)(s * T + t) << 3));
        float4 lo = row[0];
        float4 hi = row[1];
        acc[0] += lo.x; acc[1] += lo.y; acc[2] += lo.z; acc[3] += lo.w;
        acc[4] += hi.x; acc[5] += hi.y; acc[6] += hi.z; acc[7] += hi.w;
    }

    float* dst = (chunk == 0) ? out : (part + (size_t)(chunk - 1) * NPIX * B);
#pragma unroll
    for (int b = 0; b < B; ++b) dst[b * NPIX + p] = acc[b];
}

__device__ __forceinline__ float sum4(const float* o, const float* part, size_t i) {
    float v = o[i];
    v += part[i];
    v += part[(size_t)NPIX * B + i];
    v += part[2 * (size_t)NPIX * B + i];
    return v;
}

// Per-batch min/max over (out + 3 partials)
__global__ __launch_bounds__(1024) void das_minmax2(const float* __restrict__ o,
                                                    const float* __restrict__ part,
                                                    float* __restrict__ mm) {
    int b = blockIdx.x;
    size_t base = (size_t)b * NPIX;
    float mn = 3.0e38f, mx = -3.0e38f;
    for (int i = threadIdx.x; i < NPIX; i += 1024) {
        float v = sum4(o, part, base + i);
        mn = fminf(mn, v);
        mx = fmaxf(mx, v);
    }
    for (int off = 32; off; off >>= 1) {
        mn = fminf(mn, __shfl_down(mn, off));
        mx = fmaxf(mx, __shfl_down(mx, off));
    }
    __shared__ float smn[16], smx[16];
    int w = threadIdx.x >> 6;
    if ((threadIdx.x & 63) == 0) { smn[w] = mn; smx[w] = mx; }
    __syncthreads();
    if (threadIdx.x < 16) {
        mn = smn[threadIdx.x];
        mx = smx[threadIdx.x];
        for (int off = 8; off; off >>= 1) {
            mn = fminf(mn, __shfl_down(mn, off));
            mx = fmaxf(mx, __shfl_down(mx, off));
        }
        if (threadIdx.x == 0) { mm[2 * b] = mn; mm[2 * b + 1] = mx; }
    }
}

__global__ __launch_bounds__(256) void das_norm2(float* __restrict__ out,
                                                 const float* __restrict__ part,
                                                 const float* __restrict__ mm) {
    size_t i = (size_t)blockIdx.x * 256 + threadIdx.x;
    int b = (int)(i >> 16);
    float v  = sum4(out, part, i);
    float mn = mm[2 * b];
    float mx = mm[2 * b + 1];
    out[i] = __fdiv_rn(__fsub_rn(v, mn), __fsub_rn(mx, mn));
}

// ---------- fallback path (round-12, proven 82us, needs 128KB ws) ----------

__global__ __launch_bounds__(256) void build_tab(unsigned short* __restrict__ tab) {
    int i = blockIdx.x * 256 + threadIdx.x;
    tab[i] = (unsigned short)tof_index(i >> 8, i & 255);
}

__global__ __launch_bounds__(256) void das_accum(const float* __restrict__ data,
                                                 const int* __restrict__ sxy,
                                                 const unsigned short* __restrict__ tab,
                                                 float* __restrict__ out) {
    __shared__ int sx[S], sy[S];
    int tid = threadIdx.x;
    if (tid < S) {
        sx[tid] = sxy[2 * tid];
        sy[tid] = sxy[2 * tid + 1];
    }
    __syncthreads();
    int b  = blockIdx.x >> 8;
    int ix = blockIdx.x & 255;
    int iy = tid;
    int p  = (ix << 8) + iy;
    const float* dbase = data + b * (S * T);
    double acc = 0.0;
#pragma unroll 8
    for (int s = 0; s < S; ++s) {
        int dxi = abs(sx[s] - ix);
        int dyi = abs(sy[s] - iy);
        int t = (int)tab[(dxi << 8) + dyi];
        acc += (double)dbase[s * T + t];
    }
    out[b * NPIX + p] = (float)acc;
}

__global__ __launch_bounds__(1024) void das_minmax(const float* __restrict__ img,
                                                   float* __restrict__ mm) {
    int b = blockIdx.x;
    const float* p = img + b * NPIX;
    float mn = 3.0e38f, mx = -3.0e38f;
    for (int i = threadIdx.x; i < NPIX; i += 1024) {
        float v = p[i];
        mn = fminf(mn, v);
        mx = fmaxf(mx, v);
    }
    for (int off = 32; off; off >>= 1) {
        mn = fminf(mn, __shfl_down(mn, off));
        mx = fmaxf(mx, __shfl_down(mx, off));
    }
    __shared__ float smn[16], smx[16];
    int w = threadIdx.x >> 6;
    if ((threadIdx.x & 63) == 0) { smn[w] = mn; smx[w] = mx; }
    __syncthreads();
    if (threadIdx.x < 16) {
        mn = smn[threadIdx.x];
        mx = smx[threadIdx.x];
        for (int off = 8; off; off >>= 1) {
            mn = fminf(mn, __shfl_down(mn, off));
            mx = fmaxf(mx, __shfl_down(mx, off));
        }
        if (threadIdx.x == 0) { mm[2 * b] = mn; mm[2 * b + 1] = mx; }
    }
}

__global__ __launch_bounds__(256) void das_norm(float* __restrict__ out,
                                                const float* __restrict__ mm) {
    int i = blockIdx.x * 256 + threadIdx.x;
    int b = i >> 16;
    float mn = mm[2 * b];
    float mx = mm[2 * b + 1];
    out[i] = __fdiv_rn(__fsub_rn(out[i], mn), __fsub_rn(mx, mn));
}

extern "C" void kernel_launch(void* const* d_in, const int* in_sizes, int n_in,
                              void* d_out, int out_size, void* d_ws, size_t ws_size,
                              hipStream_t stream) {
    const float* data = (const float*)d_in[0];   // (B, S, T) fp32
    const int*   sxy  = (const int*)d_in[1];     // (S, 2) int32
    float* out = (float*)d_out;                  // (B, 256, 256) fp32

    if (ws_size >= WS_NEED) {
        // ws: [0,16MB) transposed data; [16MB,22MB) 3 fp32 partials; then mm
        float* dt   = (float*)d_ws;
        float* part = (float*)((char*)d_ws + DT_BYTES);
        float* mm   = (float*)((char*)d_ws + DT_BYTES + 3 * PART_BYTES);
        das_transpose<<<(S * T) / 256, 256, 0, stream>>>(data, dt);
        das_accum8<<<NCHUNK * 256, 256, 0, stream>>>(dt, sxy, out, part);
        das_minmax2<<<B, 1024, 0, stream>>>(out, part, mm);
        das_norm2<<<(B * NPIX) / 256, 256, 0, stream>>>(out, part, mm);
    } else {
        // proven round-12 path: u16 t-table + per-(batch,pixel) threads
        unsigned short* tab = (unsigned short*)d_ws;
        float* mm = (float*)((char*)d_ws + NPIX * sizeof(unsigned short));
        build_tab<<<NPIX / 256, 256, 0, stream>>>(tab);
        das_accum<<<B * 256, 256, 0, stream>>>(data, sxy, tab, out);
        das_minmax<<<B, 1024, 0, stream>>>(out, mm);
        das_norm<<<(B * NPIX) / 256, 256, 0, stream>>>(out, mm);
    }
}

// Round 14
// 63.394 us; speedup vs baseline: 1.5779x; 1.1362x over previous
//
#include <hip/hip_runtime.h>
#include <math.h>

// Problem constants (match reference)
constexpr int B = 8, S = 128, T = 4096;
constexpr int NPIX = 256 * 256;          // NX*NY
constexpr float RVS = 1.0f / 1550.0f;    // compile-time correctly-rounded f32
constexpr float RDT = 1.0e7f;            // fl32(1/fl32(1e-7)) == 1e7 (exact)
constexpr int NCHUNK = 8;                // sensor chunks == XCD count
constexpr int SCHUNK = S / NCHUNK;       // 16 sensors per chunk
constexpr size_t DT_BYTES   = (size_t)S * T * B * sizeof(float);      // 16 MB
constexpr size_t PART_BYTES = (size_t)NPIX * B * sizeof(float);       // 2 MB
constexpr size_t MM_OFF     = DT_BYTES + (NCHUNK - 1) * PART_BYTES;   // 30 MB
constexpr size_t WS_NEED    = MM_OFF + 64;

// Verified t-chain (round 11, absmax 0.0039): XLA f32 with x/const -> x*(1/const).
__device__ __forceinline__ int tof_index(int dxi, int dyi) {
    float ax = (float)dxi * 1e-3f;
    float ay = (float)dyi * 1e-3f;
    float px = ax * ax;
    float py = ay * ay;
    asm volatile("" : "+v"(px));         // pin rounded squares: forbid FMA
    asm volatile("" : "+v"(py));
    float d2  = px + py;
    float dis = __fsqrt_rn(d2);
    float q1  = __fmul_rn(dis, RVS);
    asm volatile("" : "+v"(q1));
    float tf  = __fmul_rn(q1, RDT);
    return (int)tf;                      // t_max ~ 2326 < 4096
}

// Orderable uint mapping for float min/max atomics (monotonic, bijective).
__device__ __forceinline__ unsigned fkey(float f) {
    unsigned u = __float_as_uint(f);
    return ((int)u < 0) ? ~u : (u | 0x80000000u);
}
__device__ __forceinline__ float funkey(unsigned k) {
    return __uint_as_float(((int)k < 0) ? (k ^ 0x80000000u) : ~k);
}

// ---------- fast path ----------

// Transpose (B,S,T) -> (S,T,B), 4 (s,t)-elements per thread (128B writes).
// Block 0 also initializes the min/max atomic keys for this launch.
__global__ __launch_bounds__(256) void das_transpose(const float* __restrict__ data,
                                                     float* __restrict__ dt,
                                                     unsigned* __restrict__ mm) {
    int tid = threadIdx.x;
    if (blockIdx.x == 0 && tid < 16) mm[tid] = (tid < 8) ? 0xFFFFFFFFu : 0u;
    size_t idx4 = ((size_t)blockIdx.x * 256 + tid) * 4;   // s*T + t, x4
    float4 v[B];
#pragma unroll
    for (int b = 0; b < B; ++b)
        v[b] = *(const float4*)(data + (size_t)b * (S * T) + idx4);
    float* o = dt + idx4 * B;
#pragma unroll
    for (int j = 0; j < 4; ++j) {
        float4 lo = make_float4((&v[0].x)[j], (&v[1].x)[j], (&v[2].x)[j], (&v[3].x)[j]);
        float4 hi = make_float4((&v[4].x)[j], (&v[5].x)[j], (&v[6].x)[j], (&v[7].x)[j]);
        *(float4*)(o + j * B)     = lo;
        *(float4*)(o + j * B + 4) = hi;
    }
}

// Delay-and-sum: one thread per pixel, 8 fp32 batch accumulators, 16 sensors
// per chunk. Swizzle puts chunk k on XCD k (round-robin dispatch), so each
// XCD's hot dt slice (16 sensors x ~2327 t x 32B ~ 1.2MB) fits its 4MB L2.
// 2048 blocks -> 8 blocks/CU -> 32 waves/CU.
__global__ __launch_bounds__(256, 8) void das_accum8(const float* __restrict__ dt,
                                                     const int* __restrict__ sxy,
                                                     float* __restrict__ out,
                                                     float* __restrict__ part) {
    unsigned bid = blockIdx.x;
    unsigned swz = (bid & 7) * 256 + (bid >> 3);  // chunk = bid&7 -> its XCD
    int chunk = swz >> 8;                         // 0..7
    int ix    = swz & 255;                        // pixel row (block-uniform)
    int iy    = threadIdx.x;                      // pixel col
    int p     = (ix << 8) + iy;

    float acc[B];
#pragma unroll
    for (int b = 0; b < B; ++b) acc[b] = 0.0f;

    int s0 = chunk * SCHUNK;
#pragma unroll
    for (int k = 0; k < SCHUNK; ++k) {
        int s = s0 + k;
        int dxi = abs(sxy[2 * s] - ix);           // uniform: SALU + s_load
        int dyi = abs(sxy[2 * s + 1] - iy);
        int t = tof_index(dxi, dyi);
        const float4* row = (const float4*)(dt + ((size_t)(s * T + t) << 3));
        float4 lo = row[0];
        float4 hi = row[1];
        acc[0] += lo.x; acc[1] += lo.y; acc[2] += lo.z; acc[3] += lo.w;
        acc[4] += hi.x; acc[5] += hi.y; acc[6] += hi.z; acc[7] += hi.w;
    }

    float* dst = (chunk == 0) ? out : (part + (size_t)(chunk - 1) * NPIX * B);
#pragma unroll
    for (int b = 0; b < B; ++b) dst[b * NPIX + p] = acc[b];
}

// Combine the 8 chunk partials into out AND per-batch min/max (atomic keys).
// 4 pixels/thread; each block spans 1024 consecutive pixels of ONE batch.
__global__ __launch_bounds__(256) void das_combine(const float* __restrict__ part,
                                                   float* __restrict__ out,
                                                   unsigned* __restrict__ mm) {
    size_t i4 = ((size_t)blockIdx.x * 256 + threadIdx.x) * 4;
    int b = (int)(i4 >> 16);
    float4 v = *(float4*)(out + i4);
#pragma unroll
    for (int c = 0; c < NCHUNK - 1; ++c) {
        float4 q = *(const float4*)(part + (size_t)c * NPIX * B + i4);
        v.x += q.x; v.y += q.y; v.z += q.z; v.w += q.w;
    }
    *(float4*)(out + i4) = v;

    float mn = fminf(fminf(v.x, v.y), fminf(v.z, v.w));
    float mx = fmaxf(fmaxf(v.x, v.y), fmaxf(v.z, v.w));
    for (int off = 32; off; off >>= 1) {
        mn = fminf(mn, __shfl_down(mn, off));
        mx = fmaxf(mx, __shfl_down(mx, off));
    }
    __shared__ float smn[4], smx[4];
    int w = threadIdx.x >> 6;
    if ((threadIdx.x & 63) == 0) { smn[w] = mn; smx[w] = mx; }
    __syncthreads();
    if (threadIdx.x == 0) {
        mn = fminf(fminf(smn[0], smn[1]), fminf(smn[2], smn[3]));
        mx = fmaxf(fmaxf(smx[0], smx[1]), fmaxf(smx[2], smx[3]));
        atomicMin(&mm[b], fkey(mn));
        atomicMax(&mm[8 + b], fkey(mx));
    }
}

// Per-batch min-max normalization, 4 pixels/thread, in place.
__global__ __launch_bounds__(256) void das_norm3(float* __restrict__ out,
                                                 const unsigned* __restrict__ mm) {
    size_t i4 = ((size_t)blockIdx.x * 256 + threadIdx.x) * 4;
    int b = (int)(i4 >> 16);
    float mn = funkey(mm[b]);
    float rs = __fsub_rn(funkey(mm[8 + b]), mn);
    float4 v = *(float4*)(out + i4);
    v.x = __fdiv_rn(__fsub_rn(v.x, mn), rs);
    v.y = __fdiv_rn(__fsub_rn(v.y, mn), rs);
    v.z = __fdiv_rn(__fsub_rn(v.z, mn), rs);
    v.w = __fdiv_rn(__fsub_rn(v.w, mn), rs);
    *(float4*)(out + i4) = v;
}

// ---------- fallback path (round-12, proven, needs 128KB ws) ----------

__global__ __launch_bounds__(256) void build_tab(unsigned short* __restrict__ tab) {
    int i = blockIdx.x * 256 + threadIdx.x;
    tab[i] = (unsigned short)tof_index(i >> 8, i & 255);
}

__global__ __launch_bounds__(256) void das_accum(const float* __restrict__ data,
                                                 const int* __restrict__ sxy,
                                                 const unsigned short* __restrict__ tab,
                                                 float* __restrict__ out) {
    __shared__ int sx[S], sy[S];
    int tid = threadIdx.x;
    if (tid < S) { sx[tid] = sxy[2 * tid]; sy[tid] = sxy[2 * tid + 1]; }
    __syncthreads();
    int b = blockIdx.x >> 8, ix = blockIdx.x & 255, iy = tid;
    int p = (ix << 8) + iy;
    const float* dbase = data + b * (S * T);
    double acc = 0.0;
#pragma unroll 8
    for (int s = 0; s < S; ++s) {
        int t = (int)tab[(abs(sx[s] - ix) << 8) + abs(sy[s] - iy)];
        acc += (double)dbase[s * T + t];
    }
    out[b * NPIX + p] = (float)acc;
}

__global__ __launch_bounds__(1024) void das_minmax(const float* __restrict__ img,
                                                   float* __restrict__ mmf) {
    int b = blockIdx.x;
    const float* p = img + b * NPIX;
    float mn = 3.0e38f, mx = -3.0e38f;
    for (int i = threadIdx.x; i < NPIX; i += 1024) {
        float v = p[i];
        mn = fminf(mn, v); mx = fmaxf(mx, v);
    }
    for (int off = 32; off; off >>= 1) {
        mn = fminf(mn, __shfl_down(mn, off));
        mx = fmaxf(mx, __shfl_down(mx, off));
    }
    __shared__ float smn[16], smx[16];
    int w = threadIdx.x >> 6;
    if ((threadIdx.x & 63) == 0) { smn[w] = mn; smx[w] = mx; }
    __syncthreads();
    if (threadIdx.x < 16) {
        mn = smn[threadIdx.x]; mx = smx[threadIdx.x];
        for (int off = 8; off; off >>= 1) {
            mn = fminf(mn, __shfl_down(mn, off));
            mx = fmaxf(mx, __shfl_down(mx, off));
        }
        if (threadIdx.x == 0) { mmf[2 * b] = mn; mmf[2 * b + 1] = mx; }
    }
}

__global__ __launch_bounds__(256) void das_norm(float* __restrict__ out,
                                                const float* __restrict__ mmf) {
    int i = blockIdx.x * 256 + threadIdx.x;
    int b = i >> 16;
    out[i] = __fdiv_rn(__fsub_rn(out[i], mmf[2 * b]), __fsub_rn(mmf[2 * b + 1], mmf[2 * b]));
}

extern "C" void kernel_launch(void* const* d_in, const int* in_sizes, int n_in,
                              void* d_out, int out_size, void* d_ws, size_t ws_size,
                              hipStream_t stream) {
    const float* data = (const float*)d_in[0];   // (B, S, T) fp32
    const int*   sxy  = (const int*)d_in[1];     // (S, 2) int32
    float* out = (float*)d_out;                  // (B, 256, 256) fp32

    if (ws_size >= WS_NEED) {
        float*    dt   = (float*)d_ws;
        float*    part = (float*)((char*)d_ws + DT_BYTES);
        unsigned* mm   = (unsigned*)((char*)d_ws + MM_OFF);
        das_transpose<<<(S * T) / 1024, 256, 0, stream>>>(data, dt, mm);
        das_accum8<<<NCHUNK * 256, 256, 0, stream>>>(dt, sxy, out, part);
        das_combine<<<(B * NPIX) / 1024, 256, 0, stream>>>(part, out, mm);
        das_norm3<<<(B * NPIX) / 1024, 256, 0, stream>>>(out, mm);
    } else {
        unsigned short* tab = (unsigned short*)d_ws;
        float* mmf = (float*)((char*)d_ws + NPIX * sizeof(unsigned short));
        build_tab<<<NPIX / 256, 256, 0, stream>>>(tab);
        das_accum<<<B * 256, 256, 0, stream>>>(data, sxy, tab, out);
        das_minmax<<<B, 1024, 0, stream>>>(out, mmf);
        das_norm<<<(B * NPIX) / 256, 256, 0, stream>>>(out, mmf);
    }
}

// Round 15
// 55.050 us; speedup vs baseline: 1.8171x; 1.1516x over previous
//
#include <hip/hip_runtime.h>
#include <math.h>

// Problem constants (match reference)
constexpr int B = 8, S = 128, T = 4096;
constexpr int NPIX = 256 * 256;          // NX*NY
constexpr float RVS = 1.0f / 1550.0f;    // compile-time correctly-rounded f32
constexpr float RDT = 1.0e7f;            // fl32(1/fl32(1e-7)) == 1e7 (exact)
constexpr int NCHUNK = 8;                // sensor chunks == XCD count
constexpr int SCHUNK = S / NCHUNK;       // 16 sensors per chunk
constexpr size_t DT_BYTES   = (size_t)S * T * B * sizeof(float);      // 16 MB
constexpr size_t PART_BYTES = (size_t)NPIX * B * sizeof(float);       // 2 MB
constexpr size_t MM_OFF     = DT_BYTES + (NCHUNK - 1) * PART_BYTES;   // 30 MB
constexpr size_t WS_NEED    = MM_OFF + 64;

// Verified t-chain (round 11, absmax 0.0039): XLA f32 with x/const -> x*(1/const).
__device__ __forceinline__ int tof_index(int dxi, int dyi) {
    float ax = (float)dxi * 1e-3f;
    float ay = (float)dyi * 1e-3f;
    float px = ax * ax;
    float py = ay * ay;
    asm volatile("" : "+v"(px));         // pin rounded squares: forbid FMA
    asm volatile("" : "+v"(py));
    float d2  = px + py;
    float dis = __fsqrt_rn(d2);
    float q1  = __fmul_rn(dis, RVS);
    asm volatile("" : "+v"(q1));
    float tf  = __fmul_rn(q1, RDT);
    return (int)tf;                      // t_max ~ 2326 < 4096
}

// Orderable uint mapping for float min/max atomics (monotonic, bijective).
__device__ __forceinline__ unsigned fkey(float f) {
    unsigned u = __float_as_uint(f);
    return ((int)u < 0) ? ~u : (u | 0x80000000u);
}
__device__ __forceinline__ float funkey(unsigned k) {
    return __uint_as_float(((int)k < 0) ? (k ^ 0x80000000u) : ~k);
}

// ---------- fast path ----------

// Transpose (B,S,T) -> (S,T,B), 4 (s,t)-elements per thread (128B writes).
// Block 0 also initializes the min/max atomic keys for this launch.
__global__ __launch_bounds__(256) void das_transpose(const float* __restrict__ data,
                                                     float* __restrict__ dt,
                                                     unsigned* __restrict__ mm) {
    int tid = threadIdx.x;
    if (blockIdx.x == 0 && tid < 16) mm[tid] = (tid < 8) ? 0xFFFFFFFFu : 0u;
    size_t idx4 = ((size_t)blockIdx.x * 256 + tid) * 4;   // s*T + t, x4
    float4 v[B];
#pragma unroll
    for (int b = 0; b < B; ++b)
        v[b] = *(const float4*)(data + (size_t)b * (S * T) + idx4);
    float* o = dt + idx4 * B;
#pragma unroll
    for (int j = 0; j < 4; ++j) {
        float4 lo = make_float4((&v[0].x)[j], (&v[1].x)[j], (&v[2].x)[j], (&v[3].x)[j]);
        float4 hi = make_float4((&v[4].x)[j], (&v[5].x)[j], (&v[6].x)[j], (&v[7].x)[j]);
        *(float4*)(o + j * B)     = lo;
        *(float4*)(o + j * B + 4) = hi;
    }
}

// Delay-and-sum: one thread per pixel, 8 fp32 batch accumulators.
// Each wave owns an 8x8 pixel tile (block = 16x16 tile, 4 waves): t-span
// within a wave-load drops from ~400 rows (row-wave) to ~70 clustered rows
// -> ~3x fewer L2 lines per gather. Chunk k -> XCD k via round-robin
// dispatch (bid&7), so each XCD's hot dt slice (~1.2MB) stays L2-resident;
// output stores are non-temporal to avoid evicting it.
__global__ __launch_bounds__(256, 8) void das_accum8(const float* __restrict__ dt,
                                                     const int* __restrict__ sxy,
                                                     float* __restrict__ out,
                                                     float* __restrict__ part) {
    unsigned bid = blockIdx.x;
    int chunk = bid & 7;                          // -> XCD chunk
    int tile  = bid >> 3;                         // 0..255 (16x16 tile grid)
    int tid   = threadIdx.x;
    int l = tid & 63, w = tid >> 6;
    int ix = ((tile >> 4) << 4) + ((w >> 1) << 3) + (l >> 3);
    int iy = ((tile & 15) << 4) + ((w & 1) << 3) + (l & 7);
    int p  = (ix << 8) + iy;

    float acc[B];
#pragma unroll
    for (int b = 0; b < B; ++b) acc[b] = 0.0f;

    int s0 = chunk * SCHUNK;
#pragma unroll
    for (int k = 0; k < SCHUNK; ++k) {
        int s = s0 + k;
        int dxi = abs(sxy[2 * s] - ix);           // sxy: uniform s_load
        int dyi = abs(sxy[2 * s + 1] - iy);
        int t = tof_index(dxi, dyi);
        const float4* row = (const float4*)(dt + ((size_t)(s * T + t) << 3));
        float4 lo = row[0];
        float4 hi = row[1];
        acc[0] += lo.x; acc[1] += lo.y; acc[2] += lo.z; acc[3] += lo.w;
        acc[4] += hi.x; acc[5] += hi.y; acc[6] += hi.z; acc[7] += hi.w;
    }

    float* dst = (chunk == 0) ? out : (part + (size_t)(chunk - 1) * NPIX * B);
#pragma unroll
    for (int b = 0; b < B; ++b)
        __builtin_nontemporal_store(acc[b], dst + b * NPIX + p);
}

// Combine the 8 chunk partials into out AND per-batch min/max (atomic keys).
// 4 pixels/thread; each block spans 1024 consecutive pixels of ONE batch.
__global__ __launch_bounds__(256) void das_combine(const float* __restrict__ part,
                                                   float* __restrict__ out,
                                                   unsigned* __restrict__ mm) {
    size_t i4 = ((size_t)blockIdx.x * 256 + threadIdx.x) * 4;
    int b = (int)(i4 >> 16);
    float4 v = *(float4*)(out + i4);
#pragma unroll
    for (int c = 0; c < NCHUNK - 1; ++c) {
        const float* q = part + (size_t)c * NPIX * B + i4;
        v.x += __builtin_nontemporal_load(q);
        v.y += __builtin_nontemporal_load(q + 1);
        v.z += __builtin_nontemporal_load(q + 2);
        v.w += __builtin_nontemporal_load(q + 3);
    }
    *(float4*)(out + i4) = v;

    float mn = fminf(fminf(v.x, v.y), fminf(v.z, v.w));
    float mx = fmaxf(fmaxf(v.x, v.y), fmaxf(v.z, v.w));
    for (int off = 32; off; off >>= 1) {
        mn = fminf(mn, __shfl_down(mn, off));
        mx = fmaxf(mx, __shfl_down(mx, off));
    }
    __shared__ float smn[4], smx[4];
    int w = threadIdx.x >> 6;
    if ((threadIdx.x & 63) == 0) { smn[w] = mn; smx[w] = mx; }
    __syncthreads();
    if (threadIdx.x == 0) {
        mn = fminf(fminf(smn[0], smn[1]), fminf(smn[2], smn[3]));
        mx = fmaxf(fmaxf(smx[0], smx[1]), fmaxf(smx[2], smx[3]));
        atomicMin(&mm[b], fkey(mn));
        atomicMax(&mm[8 + b], fkey(mx));
    }
}

// Per-batch min-max normalization, 4 pixels/thread, in place.
__global__ __launch_bounds__(256) void das_norm3(float* __restrict__ out,
                                                 const unsigned* __restrict__ mm) {
    size_t i4 = ((size_t)blockIdx.x * 256 + threadIdx.x) * 4;
    int b = (int)(i4 >> 16);
    float mn = funkey(mm[b]);
    float rs = __fsub_rn(funkey(mm[8 + b]), mn);
    float4 v = *(float4*)(out + i4);
    v.x = __fdiv_rn(__fsub_rn(v.x, mn), rs);
    v.y = __fdiv_rn(__fsub_rn(v.y, mn), rs);
    v.z = __fdiv_rn(__fsub_rn(v.z, mn), rs);
    v.w = __fdiv_rn(__fsub_rn(v.w, mn), rs);
    *(float4*)(out + i4) = v;
}

// ---------- fallback path (round-12, proven, needs 128KB ws) ----------

__global__ __launch_bounds__(256) void build_tab(unsigned short* __restrict__ tab) {
    int i = blockIdx.x * 256 + threadIdx.x;
    tab[i] = (unsigned short)tof_index(i >> 8, i & 255);
}

__global__ __launch_bounds__(256) void das_accum(const float* __restrict__ data,
                                                 const int* __restrict__ sxy,
                                                 const unsigned short* __restrict__ tab,
                                                 float* __restrict__ out) {
    __shared__ int sx[S], sy[S];
    int tid = threadIdx.x;
    if (tid < S) { sx[tid] = sxy[2 * tid]; sy[tid] = sxy[2 * tid + 1]; }
    __syncthreads();
    int b = blockIdx.x >> 8, ix = blockIdx.x & 255, iy = tid;
    int p = (ix << 8) + iy;
    const float* dbase = data + b * (S * T);
    double acc = 0.0;
#pragma unroll 8
    for (int s = 0; s < S; ++s) {
        int t = (int)tab[(abs(sx[s] - ix) << 8) + abs(sy[s] - iy)];
        acc += (double)dbase[s * T + t];
    }
    out[b * NPIX + p] = (float)acc;
}

__global__ __launch_bounds__(1024) void das_minmax(const float* __restrict__ img,
                                                   float* __restrict__ mmf) {
    int b = blockIdx.x;
    const float* p = img + b * NPIX;
    float mn = 3.0e38f, mx = -3.0e38f;
    for (int i = threadIdx.x; i < NPIX; i += 1024) {
        float v = p[i];
        mn = fminf(mn, v); mx = fmaxf(mx, v);
    }
    for (int off = 32; off; off >>= 1) {
        mn = fminf(mn, __shfl_down(mn, off));
        mx = fmaxf(mx, __shfl_down(mx, off));
    }
    __shared__ float smn[16], smx[16];
    int w = threadIdx.x >> 6;
    if ((threadIdx.x & 63) == 0) { smn[w] = mn; smx[w] = mx; }
    __syncthreads();
    if (threadIdx.x < 16) {
        mn = smn[threadIdx.x]; mx = smx[threadIdx.x];
        for (int off = 8; off; off >>= 1) {
            mn = fminf(mn, __shfl_down(mn, off));
            mx = fmaxf(mx, __shfl_down(mx, off));
        }
        if (threadIdx.x == 0) { mmf[2 * b] = mn; mmf[2 * b + 1] = mx; }
    }
}

__global__ __launch_bounds__(256) void das_norm(float* __restrict__ out,
                                                const float* __restrict__ mmf) {
    int i = blockIdx.x * 256 + threadIdx.x;
    int b = i >> 16;
    out[i] = __fdiv_rn(__fsub_rn(out[i], mmf[2 * b]), __fsub_rn(mmf[2 * b + 1], mmf[2 * b]));
}

extern "C" void kernel_launch(void* const* d_in, const int* in_sizes, int n_in,
                              void* d_out, int out_size, void* d_ws, size_t ws_size,
                              hipStream_t stream) {
    const float* data = (const float*)d_in[0];   // (B, S, T) fp32
    const int*   sxy  = (const int*)d_in[1];     // (S, 2) int32
    float* out = (float*)d_out;                  // (B, 256, 256) fp32

    if (ws_size >= WS_NEED) {
        float*    dt   = (float*)d_ws;
        float*    part = (float*)((char*)d_ws + DT_BYTES);
        unsigned* mm   = (unsigned*)((char*)d_ws + MM_OFF);
        das_transpose<<<(S * T) / 1024, 256, 0, stream>>>(data, dt, mm);
        das_accum8<<<NCHUNK * 256, 256, 0, stream>>>(dt, sxy, out, part);
        das_combine<<<(B * NPIX) / 1024, 256, 0, stream>>>(part, out, mm);
        das_norm3<<<(B * NPIX) / 1024, 256, 0, stream>>>(out, mm);
    } else {
        unsigned short* tab = (unsigned short*)d_ws;
        float* mmf = (float*)((char*)d_ws + NPIX * sizeof(unsigned short));
        build_tab<<<NPIX / 256, 256, 0, stream>>>(tab);
        das_accum<<<B * 256, 256, 0, stream>>>(data, sxy, tab, out);
        das_minmax<<<B, 1024, 0, stream>>>(out, mmf);
        das_norm<<<(B * NPIX) / 256, 256, 0, stream>>>(out, mmf);
    }
}